// Round 6
// baseline (445.069 us; speedup 1.0000x reference)
//
#include <hip/hip_runtime.h>

#define DI __device__ __forceinline__

typedef __bf16 bf16_t;
typedef __bf16 bf16x4 __attribute__((ext_vector_type(4)));
typedef __bf16 bf16x8 __attribute__((ext_vector_type(8)));
typedef float f32x4 __attribute__((ext_vector_type(4)));
typedef unsigned long long u64;

// Problem constants
// B=64, N=512, F=64, H=128, FO=64, K=16

DI bf16_t f2b(float f) {
  unsigned u = __float_as_uint(f);
  unsigned r = (u + 0x7fffu + ((u >> 16) & 1u)) >> 16;
  return __builtin_bit_cast(bf16_t, (unsigned short)r);
}
DI float b2f(bf16_t h) {
  return __uint_as_float(((unsigned)__builtin_bit_cast(unsigned short, h)) << 16);
}
DI f32x4 zero4() { f32x4 z = {0.f, 0.f, 0.f, 0.f}; return z; }

DI bf16x8 make_frag(const float* p, bool wantlo) {
  float4 v0 = *(const float4*)p;
  float4 v1 = *(const float4*)(p + 4);
  float vv[8] = {v0.x, v0.y, v0.z, v0.w, v1.x, v1.y, v1.z, v1.w};
  bf16x8 a;
#pragma unroll
  for (int j = 0; j < 8; ++j) {
    bf16_t hi = f2b(vv[j]);
    a[j] = wantlo ? f2b(vv[j] - b2f(hi)) : hi;
  }
  return a;
}

DI u64 u64min(u64 a, u64 b) { return a < b ? a : b; }
// ctrl must be an ICE for __builtin_amdgcn_update_dpp -> template parameter.
template <int CTRL>
DI u64 dpp_u64(u64 v) {
  int lo = (int)(unsigned)(v & 0xffffffffull);
  int hi = (int)(unsigned)(v >> 32);
  int tlo = __builtin_amdgcn_update_dpp(0, lo, CTRL, 0xF, 0xF, true);
  int thi = __builtin_amdgcn_update_dpp(0, hi, CTRL, 0xF, 0xF, true);
  return (((u64)(unsigned)thi) << 32) | (unsigned)tlo;
}
DI u64 rdlane_u64(u64 v, int l) {
  unsigned lo = (unsigned)__builtin_amdgcn_readlane((int)(unsigned)(v & 0xffffffffull), l);
  unsigned hi = (unsigned)__builtin_amdgcn_readlane((int)(unsigned)(v >> 32), l);
  return (((u64)hi) << 32) | lo;
}
// Wave64 u64 min, result wave-uniform. DPP ctrl set verified in r4:
// 0xB1 quad_perm(1,0,3,2), 0x4E quad_perm(2,3,0,1), 0x141 half_mirror, 0x140 mirror.
DI u64 wave_min_u64(u64 v) {
  v = u64min(v, dpp_u64<0xB1>(v));
  v = u64min(v, dpp_u64<0x4E>(v));
  v = u64min(v, dpp_u64<0x141>(v));
  v = u64min(v, dpp_u64<0x140>(v));
  u64 a = rdlane_u64(v, 0), b = rdlane_u64(v, 16);
  u64 c = rdlane_u64(v, 32), d = rdlane_u64(v, 48);
  return u64min(u64min(a, b), u64min(c, d));
}
DI void cas(u64& a, u64& b) { u64 mn = a < b ? a : b; u64 mx = a < b ? b : a; a = mn; b = mx; }

// ---------------- Kernel P: pack weights into split-bf16 MFMA B-fragment layout ----
__global__ void kpack(const float* __restrict__ We1, const float* __restrict__ We2,
                      const float* __restrict__ Wn1, const float* __restrict__ Wn2,
                      bf16_t* __restrict__ W1p, bf16_t* __restrict__ W2p,
                      bf16_t* __restrict__ Wn1p, bf16_t* __restrict__ Wn2p) {
  int p = blockIdx.x * 256 + threadIdx.x;  // 0..16383
  const float* W; bf16_t* dst; int K, Nn, local, mode;
  if (p < 4096)       { W = We1; dst = W1p;  K = 128; Nn = 128; mode = 0; local = p; }
  else if (p < 8192)  { W = We2; dst = W2p;  K = 128; Nn = 128; mode = 1; local = p - 4096; }
  else if (p < 14336) { W = Wn1; dst = Wn1p; K = 192; Nn = 128; mode = 0; local = p - 8192; }
  else                { W = Wn2; dst = Wn2p; K = 128; Nn = 64;  mode = 1; local = p - 14336; }
  int lane = local & 63;
  int nnt = (Nn >> 4);
  int chunk = local >> 6;
  int nt = chunk % nnt;
  int s = chunk / nnt;
  int n = nt * 16 + (lane & 15);
  int kbase = s * 32 + ((lane >> 4) * 8);
  bf16x8 v;
#pragma unroll
  for (int j = 0; j < 8; ++j) {
    int kp = kbase + j;
    int region = kp / K;
    int kk = kp - region * K;
    float w = W[kk * Nn + n];
    bf16_t hi = f2b(w);
    v[j] = (mode == 1 && region == 1) ? f2b(w - b2f(hi)) : hi;
  }
  *(bf16x8*)(dst + (size_t)local * 8) = v;
}

// ---------------- Kernel A: x, xhi/xlo planes, sq, per-batch compaction ------------
__global__ void __launch_bounds__(256) kprep(const float* __restrict__ nodes,
    const int* __restrict__ mask, float* __restrict__ x,
    bf16_t* __restrict__ xhi, bf16_t* __restrict__ xlo,
    float* __restrict__ sq, int* __restrict__ vlist, int* __restrict__ vcnt) {
  const int b = blockIdx.x, t = threadIdx.x, lane = t & 63, w = t >> 6;
  __shared__ int cnts[8];
  __shared__ int basep[8];
  unsigned long long bal[2]; int flag[2];
#pragma unroll
  for (int h = 0; h < 2; ++h) {
    const int n = h * 256 + t;
    const size_t ro = (size_t)(b * 512 + n) * 64;
    const int mk = mask[b * 512 + n];
    const float fm = (float)mk;
    float s = 0.f;
#pragma unroll
    for (int c = 0; c < 64; c += 4) {
      float4 v = *(const float4*)(nodes + ro + c);
      v.x *= fm; v.y *= fm; v.z *= fm; v.w *= fm;
      *(float4*)(x + ro + c) = v;
      float vv[4] = {v.x, v.y, v.z, v.w};
      bf16x4 hh, ll;
#pragma unroll
      for (int k = 0; k < 4; ++k) {
        bf16_t hi = f2b(vv[k]);
        hh[k] = hi;
        ll[k] = f2b(vv[k] - b2f(hi));
      }
      *(bf16x4*)(xhi + ro + c) = hh;
      *(bf16x4*)(xlo + ro + c) = ll;
      s += v.x * v.x + v.y * v.y + v.z * v.z + v.w * v.w;
    }
    sq[b * 512 + n] = s;
    flag[h] = (mk != 0);
    bal[h] = __ballot(flag[h]);
    if (lane == 0) cnts[h * 4 + w] = __popcll(bal[h]);
  }
  __syncthreads();
  if (t == 0) {
    int a = 0;
    for (int c = 0; c < 8; ++c) { basep[c] = a; a += cnts[c]; }
    vcnt[b] = a;
  }
  __syncthreads();
#pragma unroll
  for (int h = 0; h < 2; ++h) {
    if (flag[h]) {
      const unsigned long long lt = (lane == 0) ? 0ull : (~0ull >> (64 - lane));
      const int pos = basep[h * 4 + w] + __popcll(bal[h] & lt);
      vlist[b * 512 + pos] = h * 256 + t;
    }
  }
}

// ---------------- Kernel B: distances + top-16 (self excluded) ---------------------
// Per receiver: build per-lane (dist<<32|idx) u64 keys excluding self, Batcher-sort
// the 8 lane slots, then 16 rounds of {u64 wave-min over heads, predicated pop}.
// Equivalent to jax.lax.top_k(-dist,K+1)[1:] (ascending (dist,idx), drop self=rank0).
__global__ void __launch_bounds__(256, 4) kknn(const float* __restrict__ x,
    const float* __restrict__ sq, const int* __restrict__ vlist,
    const int* __restrict__ vcnt, int* __restrict__ idxg) {
  const int b = blockIdx.x & 63, tile = blockIdx.x >> 6;
  const int nv = vcnt[b];
  if (tile * 16 >= nv) return;  // block-uniform, before any barrier
  const int t = threadIdx.x, lane = t & 63, w = t >> 6;
  __shared__ float sqs[512];
  __shared__ int vls[512];
  __shared__ __align__(16) float xr[16 * 64];   // 4 KB receiver rows
  __shared__ __align__(16) float xc[64 * 68];   // 17.4 KB candidate chunk
  for (int i = t; i < 512; i += 256) { sqs[i] = sq[b * 512 + i]; vls[i] = vlist[b * 512 + i]; }
  __syncthreads();
  const float* xb = x + (size_t)b * 512 * 64;
  // stage 16 receiver rows: 16 threads per row
  {
    const int r = t >> 4, f4 = (t & 15) * 4;
    const int slot = tile * 16 + r;
    const int row = vls[slot < nv ? slot : 0];
    *(float4*)(xr + r * 64 + f4) = *(const float4*)(xb + (size_t)row * 64 + f4);
  }
  int rn[4]; bool vr[4];
#pragma unroll
  for (int i = 0; i < 4; ++i) {
    const int slot = tile * 16 + w * 4 + i;
    vr[i] = (slot < nv);
    rn[i] = vls[slot < nv ? slot : 0];
  }

  float accd[4][8];
#pragma unroll
  for (int i = 0; i < 4; ++i)
#pragma unroll
    for (int j = 0; j < 8; ++j) accd[i][j] = 0.f;

#pragma unroll
  for (int cb = 0; cb < 8; ++cb) {
    if (cb * 64 < nv) {  // uniform
      __syncthreads();
      {
        const int f4 = (t & 15) * 4;
#pragma unroll
        for (int p = 0; p < 4; ++p) {
          const int cl = (t >> 4) + p * 16;
          const int c = cb * 64 + cl;
          if (c < nv)
            *(float4*)(xc + cl * 68 + f4) = *(const float4*)(xb + (size_t)vls[c] * 64 + f4);
        }
      }
      __syncthreads();
#pragma unroll
      for (int fc = 0; fc < 16; ++fc) {
        const float4 xm = *(const float4*)(xc + lane * 68 + fc * 4);
#pragma unroll
        for (int i = 0; i < 4; ++i) {
          const float4 xn = *(const float4*)(xr + (w * 4 + i) * 64 + fc * 4);  // broadcast
          float a = accd[i][cb];
          a = fmaf(xn.x, xm.x, a);
          a = fmaf(xn.y, xm.y, a);
          a = fmaf(xn.z, xm.z, a);
          a = fmaf(xn.w, xm.w, a);
          accd[i][cb] = a;
        }
      }
    }
  }

  const u64 INF64 = ~0ull;
  // selection: receivers processed sequentially (small live set -> high occupancy)
#pragma unroll
  for (int i = 0; i < 4; ++i) {
    if (!vr[i]) continue;  // wave-uniform
    const int n = rn[i];
    const float sqn = sqs[n];
    u64 slots[8];
#pragma unroll
    for (int j = 0; j < 8; ++j) {
      slots[j] = INF64;
      if (j * 64 < nv) {  // uniform
        const int c = j * 64 + lane;
        const int m = vls[c < nv ? c : 0];
        const float d = fabsf(sqn + sqs[m] - 2.f * accd[i][j]);
        if (c < nv && m != n)
          slots[j] = (((u64)__float_as_uint(d)) << 32) | (unsigned)m;
      }
    }
    // Batcher odd-even mergesort, 8 elements, 19 comparators, depth 6
    cas(slots[0], slots[1]); cas(slots[2], slots[3]); cas(slots[4], slots[5]); cas(slots[6], slots[7]);
    cas(slots[0], slots[2]); cas(slots[1], slots[3]); cas(slots[4], slots[6]); cas(slots[5], slots[7]);
    cas(slots[1], slots[2]); cas(slots[5], slots[6]);
    cas(slots[0], slots[4]); cas(slots[1], slots[5]); cas(slots[2], slots[6]); cas(slots[3], slots[7]);
    cas(slots[2], slots[4]); cas(slots[3], slots[5]);
    cas(slots[1], slots[2]); cas(slots[3], slots[4]); cas(slots[5], slots[6]);

    int res = n;
#pragma unroll
    for (int ts = 0; ts < 16; ++ts) {
      const u64 wmin = wave_min_u64(slots[0]);
      if (lane == ts) res = (wmin == INF64) ? n : (int)(unsigned)(wmin & 0xffffffffull);
      const bool win = (wmin != INF64) && (slots[0] == wmin);
#pragma unroll
      for (int k2 = 0; k2 < 7; ++k2) slots[k2] = win ? slots[k2 + 1] : slots[k2];
      slots[7] = win ? INF64 : slots[7];
    }
    if (lane < 16) idxg[((size_t)b * 512 + n) * 16 + lane] = res;
  }
}

// ---------------- Kernel C: edge MLP over COMPACTED valid receivers ----------------
// Weights staged in 16 KB phases (2 slabs per barrier-pair): 16 barriers total.
// L1: A' = [E_hi | E_lo] from xhi/xlo planes, B' = [W1_hi; W1_hi]
// L2: A' = [H_hi | H_hi] via per-wave hfrag,  B' = [W2_hi; W2_lo]
__global__ void __launch_bounds__(256) kedge(const bf16_t* __restrict__ xhi,
    const bf16_t* __restrict__ xlo, const int* __restrict__ idxg,
    const int* __restrict__ vlist, const int* __restrict__ vcnt,
    const bf16_t* __restrict__ W1p, const bf16_t* __restrict__ W2p,
    const float* __restrict__ be1, const float* __restrict__ be2,
    float* __restrict__ pooled) {
  const int bb = blockIdx.x >> 6, tile = blockIdx.x & 63;
  const int nv = vcnt[bb];
  if (tile * 8 >= nv) return;  // block-uniform, before any barrier
  __shared__ __align__(16) bf16_t wbuf[8192];          // 16 KB: 2 slabs per phase
  __shared__ __align__(16) bf16_t hfrag[4][2][2048];   // 32 KB
  const int t = threadIdx.x, lane = t & 63, w = t >> 6;
  const int q = lane >> 4, e = lane & 15;

  int gid[2]; bool act[2]; int sv[2];
#pragma unroll
  for (int u = 0; u < 2; ++u) {
    const int slot = tile * 8 + w * 2 + u;
    act[u] = (slot < nv);
    gid[u] = act[u] ? (bb * 512 + vlist[bb * 512 + slot]) : 0;
    sv[u] = act[u] ? idxg[(size_t)gid[u] * 16 + e] : 0;
  }

  f32x4 acc[2][8];
#pragma unroll
  for (int u = 0; u < 2; ++u)
#pragma unroll
    for (int nt = 0; nt < 8; ++nt) acc[u][nt] = zero4();

  // ---- Layer 1: 4 phases x 2 slabs ----
  for (int p = 0; p < 4; ++p) {
    __syncthreads();
    {
      const uint4* src = (const uint4*)(W1p + (size_t)p * 8192);
      uint4* dst = (uint4*)wbuf;
#pragma unroll
      for (int i = 0; i < 4; ++i) dst[t + 256 * i] = src[t + 256 * i];
    }
    __syncthreads();
#pragma unroll
    for (int sl = 0; sl < 2; ++sl) {
      const int s = p * 2 + sl;
      const bool wantlo = (s >= 4);
      const int sr = s & 3, half = sr >> 1, inner = sr & 1;
      const int col = inner * 32 + q * 8;
      const bf16_t* plane = wantlo ? xlo : xhi;
      bf16x8 af[2];
#pragma unroll
      for (int u = 0; u < 2; ++u) {
        if (act[u]) {
          const int row = half ? (bb * 512 + sv[u]) : gid[u];
          af[u] = *(const bf16x8*)(plane + (size_t)row * 64 + col);
        }
      }
#pragma unroll
      for (int nt = 0; nt < 8; ++nt) {
        const bf16x8 bfv = *(const bf16x8*)(wbuf + sl * 4096 + (nt * 64 + lane) * 8);
#pragma unroll
        for (int u = 0; u < 2; ++u)
          if (act[u]) acc[u][nt] = __builtin_amdgcn_mfma_f32_16x16x32_bf16(af[u], bfv, acc[u][nt], 0, 0, 0);
      }
    }
  }

  // ---- Epilogue 1: bias+relu -> bf16 hi -> per-wave lane-linear A-frag buffer ----
#pragma unroll
  for (int u = 0; u < 2; ++u) {
    if (act[u]) {
#pragma unroll
      for (int nt = 0; nt < 8; ++nt) {
        const int cc = nt * 16 + e;
        const float bv = be1[cc];
        const int base = ((cc >> 5) * 64 + (q * 4) + 16 * ((cc >> 3) & 3)) * 8 + (cc & 7);
#pragma unroll
        for (int r = 0; r < 4; ++r) {
          float h = fmaxf(acc[u][nt][r] + bv, 0.f);
          hfrag[w][u][base + r * 8] = f2b(h);
        }
      }
    }
  }

  // ---- Layer 2: 4 phases x 2 slabs ----
#pragma unroll
  for (int u = 0; u < 2; ++u)
#pragma unroll
    for (int nt = 0; nt < 8; ++nt) acc[u][nt] = zero4();

  for (int p = 0; p < 4; ++p) {
    __syncthreads();
    {
      const uint4* src = (const uint4*)(W2p + (size_t)p * 8192);
      uint4* dst = (uint4*)wbuf;
#pragma unroll
      for (int i = 0; i < 4; ++i) dst[t + 256 * i] = src[t + 256 * i];
    }
    __syncthreads();
#pragma unroll
    for (int sl = 0; sl < 2; ++sl) {
      const int s = p * 2 + sl;
      const int f = s & 3;
      bf16x8 af[2];
#pragma unroll
      for (int u = 0; u < 2; ++u)
        if (act[u]) af[u] = *(const bf16x8*)(&hfrag[w][u][(f * 64 + lane) * 8]);
#pragma unroll
      for (int nt = 0; nt < 8; ++nt) {
        const bf16x8 bfv = *(const bf16x8*)(wbuf + sl * 4096 + (nt * 64 + lane) * 8);
#pragma unroll
        for (int u = 0; u < 2; ++u)
          if (act[u]) acc[u][nt] = __builtin_amdgcn_mfma_f32_16x16x32_bf16(af[u], bfv, acc[u][nt], 0, 0, 0);
      }
    }
  }

  // ---- Epilogue 2: bias+relu, mean over 16 edges (cnt==16 exactly) ----
#pragma unroll
  for (int u = 0; u < 2; ++u) {
    if (act[u]) {
#pragma unroll
      for (int nt = 0; nt < 8; ++nt) {
        const float bv = be2[nt * 16 + e];
        float part = 0.f;
#pragma unroll
        for (int r = 0; r < 4; ++r) part += fmaxf(acc[u][nt][r] + bv, 0.f);
        part += __shfl_xor(part, 16, 64);
        part += __shfl_xor(part, 32, 64);
        if (lane < 16) pooled[(size_t)gid[u] * 128 + nt * 16 + lane] = part * 0.0625f;
      }
    }
  }
}

// ---------------- Kernel D: node MLP (wave = 2 tiles of 16 nodes) ------------------
__global__ void __launch_bounds__(256) knode(const float* __restrict__ x,
    const float* __restrict__ pooled, const int* __restrict__ mask,
    const bf16_t* __restrict__ Wn1p, const bf16_t* __restrict__ Wn2p,
    const float* __restrict__ bn1, const float* __restrict__ bn2,
    float* __restrict__ out) {
  __shared__ __align__(16) bf16_t slab[4096];          // 8 KB
  __shared__ __align__(16) bf16_t hfrag[4][2][2048];   // 32 KB
  const int t = threadIdx.x, lane = t & 63, w = t >> 6;
  const int q = lane >> 4, e = lane & 15;
  int nodebase[2];
#pragma unroll
  for (int u = 0; u < 2; ++u) nodebase[u] = (blockIdx.x * 8 + w * 2 + u) * 16;

  f32x4 acc[2][8];
#pragma unroll
  for (int u = 0; u < 2; ++u)
#pragma unroll
    for (int nt = 0; nt < 8; ++nt) acc[u][nt] = zero4();

  // ---- Layer 1 (12 slabs) ----
  for (int s = 0; s < 12; ++s) {
    __syncthreads();
    {
      const uint4* src = (const uint4*)(Wn1p + (size_t)s * 4096);
      uint4* dst = (uint4*)slab;
      for (int i = t; i < 512; i += 256) dst[i] = src[i];
    }
    __syncthreads();
    const bool wantlo = (s >= 6);
    const int sr = wantlo ? (s - 6) : s;
    const int col = sr * 32 + q * 8;  // [0,192); region uniform per s
    bf16x8 af[2];
#pragma unroll
    for (int u = 0; u < 2; ++u) {
      const int node = nodebase[u] + e;
      const float* p = (col < 64) ? (x + (size_t)node * 64 + col)
                                  : (pooled + (size_t)node * 128 + (col - 64));
      af[u] = make_frag(p, wantlo);
    }
#pragma unroll
    for (int nt = 0; nt < 8; ++nt) {
      const bf16x8 bfv = *(const bf16x8*)(slab + (nt * 64 + lane) * 8);
#pragma unroll
      for (int u = 0; u < 2; ++u)
        acc[u][nt] = __builtin_amdgcn_mfma_f32_16x16x32_bf16(af[u], bfv, acc[u][nt], 0, 0, 0);
    }
  }

  // ---- Epilogue 1 ----
#pragma unroll
  for (int u = 0; u < 2; ++u) {
#pragma unroll
    for (int nt = 0; nt < 8; ++nt) {
      const int cc = nt * 16 + e;
      const float bv = bn1[cc];
      const int base = ((cc >> 5) * 64 + (q * 4) + 16 * ((cc >> 3) & 3)) * 8 + (cc & 7);
#pragma unroll
      for (int r = 0; r < 4; ++r) {
        float h = fmaxf(acc[u][nt][r] + bv, 0.f);
        hfrag[w][u][base + r * 8] = f2b(h);
      }
    }
  }

  // ---- Layer 2 (8 slabs of 4 KB, N=64 -> 4 ntiles) ----
  f32x4 acc2[2][4];
#pragma unroll
  for (int u = 0; u < 2; ++u)
#pragma unroll
    for (int nt = 0; nt < 4; ++nt) acc2[u][nt] = zero4();

  for (int s = 0; s < 8; ++s) {
    __syncthreads();
    {
      const uint4* src = (const uint4*)(Wn2p + (size_t)s * 2048);
      uint4* dst = (uint4*)slab;
      for (int i = t; i < 256; i += 256) dst[i] = src[i];
    }
    __syncthreads();
    const int f = s & 3;
    bf16x8 af[2];
#pragma unroll
    for (int u = 0; u < 2; ++u)
      af[u] = *(const bf16x8*)(&hfrag[w][u][(f * 64 + lane) * 8]);
#pragma unroll
    for (int nt = 0; nt < 4; ++nt) {
      const bf16x8 bfv = *(const bf16x8*)(slab + (nt * 64 + lane) * 8);
#pragma unroll
      for (int u = 0; u < 2; ++u)
        acc2[u][nt] = __builtin_amdgcn_mfma_f32_16x16x32_bf16(af[u], bfv, acc2[u][nt], 0, 0, 0);
    }
  }

  // ---- Final: + bn2, * mask, store ----
#pragma unroll
  for (int u = 0; u < 2; ++u) {
    int mm[4];
#pragma unroll
    for (int r = 0; r < 4; ++r) mm[r] = mask[nodebase[u] + q * 4 + r];
#pragma unroll
    for (int nt = 0; nt < 4; ++nt) {
      const float bv = bn2[nt * 16 + e];
#pragma unroll
      for (int r = 0; r < 4; ++r) {
        const int node = nodebase[u] + q * 4 + r;
        out[(size_t)node * 64 + nt * 16 + e] = (acc2[u][nt][r] + bv) * (float)mm[r];
      }
    }
  }
}

// ---------------- Launch ----------------
extern "C" void kernel_launch(void* const* d_in, const int* in_sizes, int n_in,
                              void* d_out, int out_size, void* d_ws, size_t ws_size,
                              hipStream_t stream) {
  const float* nodes = (const float*)d_in[0];
  const int*   mask  = (const int*)d_in[1];
  const float* We1   = (const float*)d_in[2];
  const float* be1   = (const float*)d_in[3];
  const float* We2   = (const float*)d_in[4];
  const float* be2   = (const float*)d_in[5];
  const float* Wn1   = (const float*)d_in[6];
  const float* bn1   = (const float*)d_in[7];
  const float* Wn2   = (const float*)d_in[8];
  const float* bn2   = (const float*)d_in[9];
  float* out = (float*)d_out;

  char* p = (char*)d_ws;
  auto alloc = [&](size_t bytes) -> char* {
    char* r = p;
    p += (bytes + 255) & ~(size_t)255;
    return r;
  };
  float*  x      = (float*)alloc((size_t)32768 * 64 * 4);
  bf16_t* xhi    = (bf16_t*)alloc((size_t)32768 * 64 * 2);
  bf16_t* xlo    = (bf16_t*)alloc((size_t)32768 * 64 * 2);
  float*  sq     = (float*)alloc((size_t)32768 * 4);
  int*    vlist  = (int*)alloc((size_t)32768 * 4);
  int*    vcnt   = (int*)alloc((size_t)64 * 4);
  int*    idxg   = (int*)alloc((size_t)32768 * 16 * 4);
  float*  pooled = (float*)alloc((size_t)32768 * 128 * 4);
  bf16_t* W1p    = (bf16_t*)alloc((size_t)8 * 8 * 64 * 8 * 2);
  bf16_t* W2p    = (bf16_t*)alloc((size_t)8 * 8 * 64 * 8 * 2);
  bf16_t* Wn1p   = (bf16_t*)alloc((size_t)12 * 8 * 64 * 8 * 2);
  bf16_t* Wn2p   = (bf16_t*)alloc((size_t)8 * 4 * 64 * 8 * 2);
  if ((size_t)(p - (char*)d_ws) > ws_size) return;  // workspace too small -> loud failure

  kpack<<<64, 256, 0, stream>>>(We1, We2, Wn1, Wn2, W1p, W2p, Wn1p, Wn2p);
  kprep<<<64, 256, 0, stream>>>(nodes, mask, x, xhi, xlo, sq, vlist, vcnt);
  kknn<<<2048, 256, 0, stream>>>(x, sq, vlist, vcnt, idxg);
  kedge<<<4096, 256, 0, stream>>>(xhi, xlo, idxg, vlist, vcnt, W1p, W2p, be1, be2, pooled);
  knode<<<256, 256, 0, stream>>>(x, pooled, mask, Wn1p, Wn2p, bn1, bn2, out);
}

// Round 7
// 368.353 us; speedup vs baseline: 1.2083x; 1.2083x over previous
//
#include <hip/hip_runtime.h>

#define DI __device__ __forceinline__

typedef __bf16 bf16_t;
typedef __bf16 bf16x4 __attribute__((ext_vector_type(4)));
typedef __bf16 bf16x8 __attribute__((ext_vector_type(8)));
typedef float f32x4 __attribute__((ext_vector_type(4)));
typedef unsigned long long u64;

// Problem constants
// B=64, N=512, F=64, H=128, FO=64, K=16

DI bf16_t f2b(float f) {
  unsigned u = __float_as_uint(f);
  unsigned r = (u + 0x7fffu + ((u >> 16) & 1u)) >> 16;
  return __builtin_bit_cast(bf16_t, (unsigned short)r);
}
DI float b2f(bf16_t h) {
  return __uint_as_float(((unsigned)__builtin_bit_cast(unsigned short, h)) << 16);
}
DI f32x4 zero4() { f32x4 z = {0.f, 0.f, 0.f, 0.f}; return z; }

DI bf16x8 make_frag(const float* p, bool wantlo) {
  float4 v0 = *(const float4*)p;
  float4 v1 = *(const float4*)(p + 4);
  float vv[8] = {v0.x, v0.y, v0.z, v0.w, v1.x, v1.y, v1.z, v1.w};
  bf16x8 a;
#pragma unroll
  for (int j = 0; j < 8; ++j) {
    bf16_t hi = f2b(vv[j]);
    a[j] = wantlo ? f2b(vv[j] - b2f(hi)) : hi;
  }
  return a;
}

DI u64 u64min(u64 a, u64 b) { return a < b ? a : b; }
// ctrl must be an ICE for __builtin_amdgcn_update_dpp -> template parameter.
template <int CTRL>
DI u64 dpp_u64(u64 v) {
  int lo = (int)(unsigned)(v & 0xffffffffull);
  int hi = (int)(unsigned)(v >> 32);
  int tlo = __builtin_amdgcn_update_dpp(0, lo, CTRL, 0xF, 0xF, true);
  int thi = __builtin_amdgcn_update_dpp(0, hi, CTRL, 0xF, 0xF, true);
  return (((u64)(unsigned)thi) << 32) | (unsigned)tlo;
}
DI u64 rdlane_u64(u64 v, int l) {
  unsigned lo = (unsigned)__builtin_amdgcn_readlane((int)(unsigned)(v & 0xffffffffull), l);
  unsigned hi = (unsigned)__builtin_amdgcn_readlane((int)(unsigned)(v >> 32), l);
  return (((u64)hi) << 32) | lo;
}
// Wave64 u64 min, result wave-uniform. DPP ctrl set verified on HW (r4/r6 passed):
// 0xB1 quad_perm(1,0,3,2), 0x4E quad_perm(2,3,0,1), 0x141 half_mirror, 0x140 mirror.
DI u64 wave_min_u64(u64 v) {
  v = u64min(v, dpp_u64<0xB1>(v));
  v = u64min(v, dpp_u64<0x4E>(v));
  v = u64min(v, dpp_u64<0x141>(v));
  v = u64min(v, dpp_u64<0x140>(v));
  u64 a = rdlane_u64(v, 0), b = rdlane_u64(v, 16);
  u64 c = rdlane_u64(v, 32), d = rdlane_u64(v, 48);
  return u64min(u64min(a, b), u64min(c, d));
}
DI void cas(u64& a, u64& b) { u64 mn = a < b ? a : b; u64 mx = a < b ? b : a; a = mn; b = mx; }

// ---------------- Kernel P: pack weights into split-bf16 MFMA B-fragment layout ----
__global__ void kpack(const float* __restrict__ We1, const float* __restrict__ We2,
                      const float* __restrict__ Wn1, const float* __restrict__ Wn2,
                      bf16_t* __restrict__ W1p, bf16_t* __restrict__ W2p,
                      bf16_t* __restrict__ Wn1p, bf16_t* __restrict__ Wn2p) {
  int p = blockIdx.x * 256 + threadIdx.x;  // 0..16383
  const float* W; bf16_t* dst; int K, Nn, local, mode;
  if (p < 4096)       { W = We1; dst = W1p;  K = 128; Nn = 128; mode = 0; local = p; }
  else if (p < 8192)  { W = We2; dst = W2p;  K = 128; Nn = 128; mode = 1; local = p - 4096; }
  else if (p < 14336) { W = Wn1; dst = Wn1p; K = 192; Nn = 128; mode = 0; local = p - 8192; }
  else                { W = Wn2; dst = Wn2p; K = 128; Nn = 64;  mode = 1; local = p - 14336; }
  int lane = local & 63;
  int nnt = (Nn >> 4);
  int chunk = local >> 6;
  int nt = chunk % nnt;
  int s = chunk / nnt;
  int n = nt * 16 + (lane & 15);
  int kbase = s * 32 + ((lane >> 4) * 8);
  bf16x8 v;
#pragma unroll
  for (int j = 0; j < 8; ++j) {
    int kp = kbase + j;
    int region = kp / K;
    int kk = kp - region * K;
    float w = W[kk * Nn + n];
    bf16_t hi = f2b(w);
    v[j] = (mode == 1 && region == 1) ? f2b(w - b2f(hi)) : hi;
  }
  *(bf16x8*)(dst + (size_t)local * 8) = v;
}

// ---------------- Kernel A: x, xhi/xlo planes, sq, per-batch compaction ------------
__global__ void __launch_bounds__(256) kprep(const float* __restrict__ nodes,
    const int* __restrict__ mask, float* __restrict__ x,
    bf16_t* __restrict__ xhi, bf16_t* __restrict__ xlo,
    float* __restrict__ sq, int* __restrict__ vlist, int* __restrict__ vcnt) {
  const int b = blockIdx.x, t = threadIdx.x, lane = t & 63, w = t >> 6;
  __shared__ int cnts[8];
  __shared__ int basep[8];
  unsigned long long bal[2]; int flag[2];
#pragma unroll
  for (int h = 0; h < 2; ++h) {
    const int n = h * 256 + t;
    const size_t ro = (size_t)(b * 512 + n) * 64;
    const int mk = mask[b * 512 + n];
    const float fm = (float)mk;
    float s = 0.f;
#pragma unroll
    for (int c = 0; c < 64; c += 4) {
      float4 v = *(const float4*)(nodes + ro + c);
      v.x *= fm; v.y *= fm; v.z *= fm; v.w *= fm;
      *(float4*)(x + ro + c) = v;
      float vv[4] = {v.x, v.y, v.z, v.w};
      bf16x4 hh, ll;
#pragma unroll
      for (int k = 0; k < 4; ++k) {
        bf16_t hi = f2b(vv[k]);
        hh[k] = hi;
        ll[k] = f2b(vv[k] - b2f(hi));
      }
      *(bf16x4*)(xhi + ro + c) = hh;
      *(bf16x4*)(xlo + ro + c) = ll;
      s += v.x * v.x + v.y * v.y + v.z * v.z + v.w * v.w;
    }
    sq[b * 512 + n] = s;
    flag[h] = (mk != 0);
    bal[h] = __ballot(flag[h]);
    if (lane == 0) cnts[h * 4 + w] = __popcll(bal[h]);
  }
  __syncthreads();
  if (t == 0) {
    int a = 0;
    for (int c = 0; c < 8; ++c) { basep[c] = a; a += cnts[c]; }
    vcnt[b] = a;
  }
  __syncthreads();
#pragma unroll
  for (int h = 0; h < 2; ++h) {
    if (flag[h]) {
      const unsigned long long lt = (lane == 0) ? 0ull : (~0ull >> (64 - lane));
      const int pos = basep[h * 4 + w] + __popcll(bal[h] & lt);
      vlist[b * 512 + pos] = h * 256 + t;
    }
  }
}

// ---------------- Kernel B: distances + top-16 (self excluded) ---------------------
// Per receiver: build per-lane (dist<<32|idx) u64 keys excluding self, Batcher-sort
// the 8 lane slots, then 16 rounds of {u64 wave-min over heads, predicated pop}.
// Equivalent to jax.lax.top_k(-dist,K+1)[1:] (ascending (dist,idx), drop self=rank0).
// NOTE: no min-waves launch bound — r6's (256,4) forced a 64-VGPR allocation with
// ~570 B/thread scratch spill (FETCH 186 MB, WRITE 300 MB). Natural allocation
// (~140 VGPR) runs spill-free at 3 waves/SIMD.
__global__ void __launch_bounds__(256) kknn(const float* __restrict__ x,
    const float* __restrict__ sq, const int* __restrict__ vlist,
    const int* __restrict__ vcnt, int* __restrict__ idxg) {
  const int b = blockIdx.x & 63, tile = blockIdx.x >> 6;
  const int nv = vcnt[b];
  if (tile * 16 >= nv) return;  // block-uniform, before any barrier
  const int t = threadIdx.x, lane = t & 63, w = t >> 6;
  __shared__ float sqs[512];
  __shared__ int vls[512];
  __shared__ __align__(16) float xr[16 * 64];   // 4 KB receiver rows
  __shared__ __align__(16) float xc[64 * 68];   // 17.4 KB candidate chunk
  for (int i = t; i < 512; i += 256) { sqs[i] = sq[b * 512 + i]; vls[i] = vlist[b * 512 + i]; }
  __syncthreads();
  const float* xb = x + (size_t)b * 512 * 64;
  // stage 16 receiver rows: 16 threads per row
  {
    const int r = t >> 4, f4 = (t & 15) * 4;
    const int slot = tile * 16 + r;
    const int row = vls[slot < nv ? slot : 0];
    *(float4*)(xr + r * 64 + f4) = *(const float4*)(xb + (size_t)row * 64 + f4);
  }
  int rn[4]; bool vr[4];
#pragma unroll
  for (int i = 0; i < 4; ++i) {
    const int slot = tile * 16 + w * 4 + i;
    vr[i] = (slot < nv);
    rn[i] = vls[slot < nv ? slot : 0];
  }

  float accd[4][8];
#pragma unroll
  for (int i = 0; i < 4; ++i)
#pragma unroll
    for (int j = 0; j < 8; ++j) accd[i][j] = 0.f;

#pragma unroll
  for (int cb = 0; cb < 8; ++cb) {
    if (cb * 64 < nv) {  // uniform
      __syncthreads();
      {
        const int f4 = (t & 15) * 4;
#pragma unroll
        for (int p = 0; p < 4; ++p) {
          const int cl = (t >> 4) + p * 16;
          const int c = cb * 64 + cl;
          if (c < nv)
            *(float4*)(xc + cl * 68 + f4) = *(const float4*)(xb + (size_t)vls[c] * 64 + f4);
        }
      }
      __syncthreads();
#pragma unroll
      for (int fc = 0; fc < 16; ++fc) {
        const float4 xm = *(const float4*)(xc + lane * 68 + fc * 4);
#pragma unroll
        for (int i = 0; i < 4; ++i) {
          const float4 xn = *(const float4*)(xr + (w * 4 + i) * 64 + fc * 4);  // broadcast
          float a = accd[i][cb];
          a = fmaf(xn.x, xm.x, a);
          a = fmaf(xn.y, xm.y, a);
          a = fmaf(xn.z, xm.z, a);
          a = fmaf(xn.w, xm.w, a);
          accd[i][cb] = a;
        }
      }
    }
  }

  const u64 INF64 = ~0ull;
  // selection: receivers processed sequentially (small live set)
#pragma unroll
  for (int i = 0; i < 4; ++i) {
    if (!vr[i]) continue;  // wave-uniform
    const int n = rn[i];
    const float sqn = sqs[n];
    u64 slots[8];
#pragma unroll
    for (int j = 0; j < 8; ++j) {
      slots[j] = INF64;
      if (j * 64 < nv) {  // uniform
        const int c = j * 64 + lane;
        const int m = vls[c < nv ? c : 0];
        const float d = fabsf(sqn + sqs[m] - 2.f * accd[i][j]);
        if (c < nv && m != n)
          slots[j] = (((u64)__float_as_uint(d)) << 32) | (unsigned)m;
      }
    }
    // Batcher odd-even mergesort, 8 elements, 19 comparators, depth 6
    cas(slots[0], slots[1]); cas(slots[2], slots[3]); cas(slots[4], slots[5]); cas(slots[6], slots[7]);
    cas(slots[0], slots[2]); cas(slots[1], slots[3]); cas(slots[4], slots[6]); cas(slots[5], slots[7]);
    cas(slots[1], slots[2]); cas(slots[5], slots[6]);
    cas(slots[0], slots[4]); cas(slots[1], slots[5]); cas(slots[2], slots[6]); cas(slots[3], slots[7]);
    cas(slots[2], slots[4]); cas(slots[3], slots[5]);
    cas(slots[1], slots[2]); cas(slots[3], slots[4]); cas(slots[5], slots[6]);

    int res = n;
#pragma unroll
    for (int ts = 0; ts < 16; ++ts) {
      const u64 wmin = wave_min_u64(slots[0]);
      if (lane == ts) res = (wmin == INF64) ? n : (int)(unsigned)(wmin & 0xffffffffull);
      const bool win = (wmin != INF64) && (slots[0] == wmin);
#pragma unroll
      for (int k2 = 0; k2 < 7; ++k2) slots[k2] = win ? slots[k2 + 1] : slots[k2];
      slots[7] = win ? INF64 : slots[7];
    }
    if (lane < 16) idxg[((size_t)b * 512 + n) * 16 + lane] = res;
  }
}

// ---------------- Kernel C: edge MLP over COMPACTED valid receivers ----------------
// Weights staged in 16 KB phases (2 slabs per barrier-pair): 16 barriers total.
// L1: A' = [E_hi | E_lo] from xhi/xlo planes, B' = [W1_hi; W1_hi]
// L2: A' = [H_hi | H_hi] via per-wave hfrag,  B' = [W2_hi; W2_lo]
__global__ void __launch_bounds__(256) kedge(const bf16_t* __restrict__ xhi,
    const bf16_t* __restrict__ xlo, const int* __restrict__ idxg,
    const int* __restrict__ vlist, const int* __restrict__ vcnt,
    const bf16_t* __restrict__ W1p, const bf16_t* __restrict__ W2p,
    const float* __restrict__ be1, const float* __restrict__ be2,
    float* __restrict__ pooled) {
  const int bb = blockIdx.x >> 6, tile = blockIdx.x & 63;
  const int nv = vcnt[bb];
  if (tile * 8 >= nv) return;  // block-uniform, before any barrier
  __shared__ __align__(16) bf16_t wbuf[8192];          // 16 KB: 2 slabs per phase
  __shared__ __align__(16) bf16_t hfrag[4][2][2048];   // 32 KB
  const int t = threadIdx.x, lane = t & 63, w = t >> 6;
  const int q = lane >> 4, e = lane & 15;

  int gid[2]; bool act[2]; int sv[2];
#pragma unroll
  for (int u = 0; u < 2; ++u) {
    const int slot = tile * 8 + w * 2 + u;
    act[u] = (slot < nv);
    gid[u] = act[u] ? (bb * 512 + vlist[bb * 512 + slot]) : 0;
    sv[u] = act[u] ? idxg[(size_t)gid[u] * 16 + e] : 0;
  }

  f32x4 acc[2][8];
#pragma unroll
  for (int u = 0; u < 2; ++u)
#pragma unroll
    for (int nt = 0; nt < 8; ++nt) acc[u][nt] = zero4();

  // ---- Layer 1: 4 phases x 2 slabs ----
  for (int p = 0; p < 4; ++p) {
    __syncthreads();
    {
      const uint4* src = (const uint4*)(W1p + (size_t)p * 8192);
      uint4* dst = (uint4*)wbuf;
#pragma unroll
      for (int i = 0; i < 4; ++i) dst[t + 256 * i] = src[t + 256 * i];
    }
    __syncthreads();
#pragma unroll
    for (int sl = 0; sl < 2; ++sl) {
      const int s = p * 2 + sl;
      const bool wantlo = (s >= 4);
      const int sr = s & 3, half = sr >> 1, inner = sr & 1;
      const int col = inner * 32 + q * 8;
      const bf16_t* plane = wantlo ? xlo : xhi;
      bf16x8 af[2];
#pragma unroll
      for (int u = 0; u < 2; ++u) {
        if (act[u]) {
          const int row = half ? (bb * 512 + sv[u]) : gid[u];
          af[u] = *(const bf16x8*)(plane + (size_t)row * 64 + col);
        }
      }
#pragma unroll
      for (int nt = 0; nt < 8; ++nt) {
        const bf16x8 bfv = *(const bf16x8*)(wbuf + sl * 4096 + (nt * 64 + lane) * 8);
#pragma unroll
        for (int u = 0; u < 2; ++u)
          if (act[u]) acc[u][nt] = __builtin_amdgcn_mfma_f32_16x16x32_bf16(af[u], bfv, acc[u][nt], 0, 0, 0);
      }
    }
  }

  // ---- Epilogue 1: bias+relu -> bf16 hi -> per-wave lane-linear A-frag buffer ----
#pragma unroll
  for (int u = 0; u < 2; ++u) {
    if (act[u]) {
#pragma unroll
      for (int nt = 0; nt < 8; ++nt) {
        const int cc = nt * 16 + e;
        const float bv = be1[cc];
        const int base = ((cc >> 5) * 64 + (q * 4) + 16 * ((cc >> 3) & 3)) * 8 + (cc & 7);
#pragma unroll
        for (int r = 0; r < 4; ++r) {
          float h = fmaxf(acc[u][nt][r] + bv, 0.f);
          hfrag[w][u][base + r * 8] = f2b(h);
        }
      }
    }
  }

  // ---- Layer 2: 4 phases x 2 slabs ----
#pragma unroll
  for (int u = 0; u < 2; ++u)
#pragma unroll
    for (int nt = 0; nt < 8; ++nt) acc[u][nt] = zero4();

  for (int p = 0; p < 4; ++p) {
    __syncthreads();
    {
      const uint4* src = (const uint4*)(W2p + (size_t)p * 8192);
      uint4* dst = (uint4*)wbuf;
#pragma unroll
      for (int i = 0; i < 4; ++i) dst[t + 256 * i] = src[t + 256 * i];
    }
    __syncthreads();
#pragma unroll
    for (int sl = 0; sl < 2; ++sl) {
      const int s = p * 2 + sl;
      const int f = s & 3;
      bf16x8 af[2];
#pragma unroll
      for (int u = 0; u < 2; ++u)
        if (act[u]) af[u] = *(const bf16x8*)(&hfrag[w][u][(f * 64 + lane) * 8]);
#pragma unroll
      for (int nt = 0; nt < 8; ++nt) {
        const bf16x8 bfv = *(const bf16x8*)(wbuf + sl * 4096 + (nt * 64 + lane) * 8);
#pragma unroll
        for (int u = 0; u < 2; ++u)
          if (act[u]) acc[u][nt] = __builtin_amdgcn_mfma_f32_16x16x32_bf16(af[u], bfv, acc[u][nt], 0, 0, 0);
      }
    }
  }

  // ---- Epilogue 2: bias+relu, mean over 16 edges (cnt==16 exactly) ----
#pragma unroll
  for (int u = 0; u < 2; ++u) {
    if (act[u]) {
#pragma unroll
      for (int nt = 0; nt < 8; ++nt) {
        const float bv = be2[nt * 16 + e];
        float part = 0.f;
#pragma unroll
        for (int r = 0; r < 4; ++r) part += fmaxf(acc[u][nt][r] + bv, 0.f);
        part += __shfl_xor(part, 16, 64);
        part += __shfl_xor(part, 32, 64);
        if (lane < 16) pooled[(size_t)gid[u] * 128 + nt * 16 + lane] = part * 0.0625f;
      }
    }
  }
}

// ---------------- Kernel D: node MLP (wave = 2 tiles of 16 nodes) ------------------
__global__ void __launch_bounds__(256) knode(const float* __restrict__ x,
    const float* __restrict__ pooled, const int* __restrict__ mask,
    const bf16_t* __restrict__ Wn1p, const bf16_t* __restrict__ Wn2p,
    const float* __restrict__ bn1, const float* __restrict__ bn2,
    float* __restrict__ out) {
  __shared__ __align__(16) bf16_t slab[4096];          // 8 KB
  __shared__ __align__(16) bf16_t hfrag[4][2][2048];   // 32 KB
  const int t = threadIdx.x, lane = t & 63, w = t >> 6;
  const int q = lane >> 4, e = lane & 15;
  int nodebase[2];
#pragma unroll
  for (int u = 0; u < 2; ++u) nodebase[u] = (blockIdx.x * 8 + w * 2 + u) * 16;

  f32x4 acc[2][8];
#pragma unroll
  for (int u = 0; u < 2; ++u)
#pragma unroll
    for (int nt = 0; nt < 8; ++nt) acc[u][nt] = zero4();

  // ---- Layer 1 (12 slabs) ----
  for (int s = 0; s < 12; ++s) {
    __syncthreads();
    {
      const uint4* src = (const uint4*)(Wn1p + (size_t)s * 4096);
      uint4* dst = (uint4*)slab;
      for (int i = t; i < 512; i += 256) dst[i] = src[i];
    }
    __syncthreads();
    const bool wantlo = (s >= 6);
    const int sr = wantlo ? (s - 6) : s;
    const int col = sr * 32 + q * 8;  // [0,192); region uniform per s
    bf16x8 af[2];
#pragma unroll
    for (int u = 0; u < 2; ++u) {
      const int node = nodebase[u] + e;
      const float* p = (col < 64) ? (x + (size_t)node * 64 + col)
                                  : (pooled + (size_t)node * 128 + (col - 64));
      af[u] = make_frag(p, wantlo);
    }
#pragma unroll
    for (int nt = 0; nt < 8; ++nt) {
      const bf16x8 bfv = *(const bf16x8*)(slab + (nt * 64 + lane) * 8);
#pragma unroll
      for (int u = 0; u < 2; ++u)
        acc[u][nt] = __builtin_amdgcn_mfma_f32_16x16x32_bf16(af[u], bfv, acc[u][nt], 0, 0, 0);
    }
  }

  // ---- Epilogue 1 ----
#pragma unroll
  for (int u = 0; u < 2; ++u) {
#pragma unroll
    for (int nt = 0; nt < 8; ++nt) {
      const int cc = nt * 16 + e;
      const float bv = bn1[cc];
      const int base = ((cc >> 5) * 64 + (q * 4) + 16 * ((cc >> 3) & 3)) * 8 + (cc & 7);
#pragma unroll
      for (int r = 0; r < 4; ++r) {
        float h = fmaxf(acc[u][nt][r] + bv, 0.f);
        hfrag[w][u][base + r * 8] = f2b(h);
      }
    }
  }

  // ---- Layer 2 (8 slabs of 4 KB, N=64 -> 4 ntiles) ----
  f32x4 acc2[2][4];
#pragma unroll
  for (int u = 0; u < 2; ++u)
#pragma unroll
    for (int nt = 0; nt < 4; ++nt) acc2[u][nt] = zero4();

  for (int s = 0; s < 8; ++s) {
    __syncthreads();
    {
      const uint4* src = (const uint4*)(Wn2p + (size_t)s * 2048);
      uint4* dst = (uint4*)slab;
      for (int i = t; i < 256; i += 256) dst[i] = src[i];
    }
    __syncthreads();
    const int f = s & 3;
    bf16x8 af[2];
#pragma unroll
    for (int u = 0; u < 2; ++u)
      af[u] = *(const bf16x8*)(&hfrag[w][u][(f * 64 + lane) * 8]);
#pragma unroll
    for (int nt = 0; nt < 4; ++nt) {
      const bf16x8 bfv = *(const bf16x8*)(slab + (nt * 64 + lane) * 8);
#pragma unroll
      for (int u = 0; u < 2; ++u)
        acc2[u][nt] = __builtin_amdgcn_mfma_f32_16x16x32_bf16(af[u], bfv, acc2[u][nt], 0, 0, 0);
    }
  }

  // ---- Final: + bn2, * mask, store ----
#pragma unroll
  for (int u = 0; u < 2; ++u) {
    int mm[4];
#pragma unroll
    for (int r = 0; r < 4; ++r) mm[r] = mask[nodebase[u] + q * 4 + r];
#pragma unroll
    for (int nt = 0; nt < 4; ++nt) {
      const float bv = bn2[nt * 16 + e];
#pragma unroll
      for (int r = 0; r < 4; ++r) {
        const int node = nodebase[u] + q * 4 + r;
        out[(size_t)node * 64 + nt * 16 + e] = (acc2[u][nt][r] + bv) * (float)mm[r];
      }
    }
  }
}

// ---------------- Launch ----------------
extern "C" void kernel_launch(void* const* d_in, const int* in_sizes, int n_in,
                              void* d_out, int out_size, void* d_ws, size_t ws_size,
                              hipStream_t stream) {
  const float* nodes = (const float*)d_in[0];
  const int*   mask  = (const int*)d_in[1];
  const float* We1   = (const float*)d_in[2];
  const float* be1   = (const float*)d_in[3];
  const float* We2   = (const float*)d_in[4];
  const float* be2   = (const float*)d_in[5];
  const float* Wn1   = (const float*)d_in[6];
  const float* bn1   = (const float*)d_in[7];
  const float* Wn2   = (const float*)d_in[8];
  const float* bn2   = (const float*)d_in[9];
  float* out = (float*)d_out;

  char* p = (char*)d_ws;
  auto alloc = [&](size_t bytes) -> char* {
    char* r = p;
    p += (bytes + 255) & ~(size_t)255;
    return r;
  };
  float*  x      = (float*)alloc((size_t)32768 * 64 * 4);
  bf16_t* xhi    = (bf16_t*)alloc((size_t)32768 * 64 * 2);
  bf16_t* xlo    = (bf16_t*)alloc((size_t)32768 * 64 * 2);
  float*  sq     = (float*)alloc((size_t)32768 * 4);
  int*    vlist  = (int*)alloc((size_t)32768 * 4);
  int*    vcnt   = (int*)alloc((size_t)64 * 4);
  int*    idxg   = (int*)alloc((size_t)32768 * 16 * 4);
  float*  pooled = (float*)alloc((size_t)32768 * 128 * 4);
  bf16_t* W1p    = (bf16_t*)alloc((size_t)8 * 8 * 64 * 8 * 2);
  bf16_t* W2p    = (bf16_t*)alloc((size_t)8 * 8 * 64 * 8 * 2);
  bf16_t* Wn1p   = (bf16_t*)alloc((size_t)12 * 8 * 64 * 8 * 2);
  bf16_t* Wn2p   = (bf16_t*)alloc((size_t)8 * 4 * 64 * 8 * 2);
  if ((size_t)(p - (char*)d_ws) > ws_size) return;  // workspace too small -> loud failure

  kpack<<<64, 256, 0, stream>>>(We1, We2, Wn1, Wn2, W1p, W2p, Wn1p, Wn2p);
  kprep<<<64, 256, 0, stream>>>(nodes, mask, x, xhi, xlo, sq, vlist, vcnt);
  kknn<<<2048, 256, 0, stream>>>(x, sq, vlist, vcnt, idxg);
  kedge<<<4096, 256, 0, stream>>>(xhi, xlo, idxg, vlist, vcnt, W1p, W2p, be1, be2, pooled);
  knode<<<256, 256, 0, stream>>>(x, pooled, mask, Wn1p, Wn2p, bn1, bn2, out);
}

// Round 8
// 275.281 us; speedup vs baseline: 1.6168x; 1.3381x over previous
//
#include <hip/hip_runtime.h>

#define DI __device__ __forceinline__

typedef __bf16 bf16_t;
typedef __bf16 bf16x4 __attribute__((ext_vector_type(4)));
typedef __bf16 bf16x8 __attribute__((ext_vector_type(8)));
typedef float f32x4 __attribute__((ext_vector_type(4)));
typedef unsigned long long u64;

// Problem constants
// B=64, N=512, F=64, H=128, FO=64, K=16

DI bf16_t f2b(float f) {
  unsigned u = __float_as_uint(f);
  unsigned r = (u + 0x7fffu + ((u >> 16) & 1u)) >> 16;
  return __builtin_bit_cast(bf16_t, (unsigned short)r);
}
DI float b2f(bf16_t h) {
  return __uint_as_float(((unsigned)__builtin_bit_cast(unsigned short, h)) << 16);
}
DI f32x4 zero4() { f32x4 z = {0.f, 0.f, 0.f, 0.f}; return z; }

DI bf16x8 make_frag(const float* p, bool wantlo) {
  float4 v0 = *(const float4*)p;
  float4 v1 = *(const float4*)(p + 4);
  float vv[8] = {v0.x, v0.y, v0.z, v0.w, v1.x, v1.y, v1.z, v1.w};
  bf16x8 a;
#pragma unroll
  for (int j = 0; j < 8; ++j) {
    bf16_t hi = f2b(vv[j]);
    a[j] = wantlo ? f2b(vv[j] - b2f(hi)) : hi;
  }
  return a;
}

DI u64 u64min(u64 a, u64 b) { return a < b ? a : b; }
// ctrl must be an ICE for __builtin_amdgcn_update_dpp -> template parameter.
template <int CTRL>
DI u64 dpp_u64(u64 v) {
  int lo = (int)(unsigned)(v & 0xffffffffull);
  int hi = (int)(unsigned)(v >> 32);
  int tlo = __builtin_amdgcn_update_dpp(0, lo, CTRL, 0xF, 0xF, true);
  int thi = __builtin_amdgcn_update_dpp(0, hi, CTRL, 0xF, 0xF, true);
  return (((u64)(unsigned)thi) << 32) | (unsigned)tlo;
}
template <int CTRL>
DI float dpp_f32(float v) {
  int t = __builtin_amdgcn_update_dpp(0, (int)__float_as_uint(v), CTRL, 0xF, 0xF, true);
  return __uint_as_float((unsigned)t);
}
// Min over each 16-lane row; result uniform within the row. DPP ctrls verified on HW
// (r4/r6/r7): 0xB1 quad_perm(1,0,3,2), 0x4E quad_perm(2,3,0,1), 0x141 half_mirror,
// 0x140 mirror — none cross a 16-lane row.
DI u64 rowmin_u64(u64 v) {
  v = u64min(v, dpp_u64<0xB1>(v));
  v = u64min(v, dpp_u64<0x4E>(v));
  v = u64min(v, dpp_u64<0x141>(v));
  v = u64min(v, dpp_u64<0x140>(v));
  return v;
}
// Sum over each 16-lane row (butterfly); result uniform within the row.
DI float rowsum_f32(float v) {
  v += dpp_f32<0xB1>(v);
  v += dpp_f32<0x4E>(v);
  v += dpp_f32<0x141>(v);
  v += dpp_f32<0x140>(v);
  return v;
}
// Bitonic sort, 16 elements, ascending. 80 CAS, all indices compile-time.
DI void bitonic16(u64* a) {
#pragma unroll
  for (int k = 2; k <= 16; k <<= 1)
#pragma unroll
    for (int j = k >> 1; j > 0; j >>= 1)
#pragma unroll
      for (int i = 0; i < 16; ++i) {
        const int l = i ^ j;
        if (l > i) {
          const bool up = ((i & k) == 0);
          const bool sw = up ? (a[i] > a[l]) : (a[i] < a[l]);
          const u64 t0 = a[i], t1 = a[l];
          a[i] = sw ? t1 : t0;
          a[l] = sw ? t0 : t1;
        }
      }
}

// ---------------- Kernel P: pack weights into split-bf16 MFMA B-fragment layout ----
__global__ void kpack(const float* __restrict__ We1, const float* __restrict__ We2,
                      const float* __restrict__ Wn1, const float* __restrict__ Wn2,
                      bf16_t* __restrict__ W1p, bf16_t* __restrict__ W2p,
                      bf16_t* __restrict__ Wn1p, bf16_t* __restrict__ Wn2p) {
  int p = blockIdx.x * 256 + threadIdx.x;  // 0..16383
  const float* W; bf16_t* dst; int K, Nn, local, mode;
  if (p < 4096)       { W = We1; dst = W1p;  K = 128; Nn = 128; mode = 0; local = p; }
  else if (p < 8192)  { W = We2; dst = W2p;  K = 128; Nn = 128; mode = 1; local = p - 4096; }
  else if (p < 14336) { W = Wn1; dst = Wn1p; K = 192; Nn = 128; mode = 0; local = p - 8192; }
  else                { W = Wn2; dst = Wn2p; K = 128; Nn = 64;  mode = 1; local = p - 14336; }
  int lane = local & 63;
  int nnt = (Nn >> 4);
  int chunk = local >> 6;
  int nt = chunk % nnt;
  int s = chunk / nnt;
  int n = nt * 16 + (lane & 15);
  int kbase = s * 32 + ((lane >> 4) * 8);
  bf16x8 v;
#pragma unroll
  for (int j = 0; j < 8; ++j) {
    int kp = kbase + j;
    int region = kp / K;
    int kk = kp - region * K;
    float w = W[kk * Nn + n];
    bf16_t hi = f2b(w);
    v[j] = (mode == 1 && region == 1) ? f2b(w - b2f(hi)) : hi;
  }
  *(bf16x8*)(dst + (size_t)local * 8) = v;
}

// ---------------- Kernel A: x, xhi/xlo planes, sq, per-batch compaction ------------
__global__ void __launch_bounds__(256) kprep(const float* __restrict__ nodes,
    const int* __restrict__ mask, float* __restrict__ x,
    bf16_t* __restrict__ xhi, bf16_t* __restrict__ xlo,
    float* __restrict__ sq, int* __restrict__ vlist, int* __restrict__ vcnt) {
  const int b = blockIdx.x, t = threadIdx.x, lane = t & 63, w = t >> 6;
  __shared__ int cnts[8];
  __shared__ int basep[8];
  unsigned long long bal[2]; int flag[2];
#pragma unroll
  for (int h = 0; h < 2; ++h) {
    const int n = h * 256 + t;
    const size_t ro = (size_t)(b * 512 + n) * 64;
    const int mk = mask[b * 512 + n];
    const float fm = (float)mk;
    float s = 0.f;
#pragma unroll
    for (int c = 0; c < 64; c += 4) {
      float4 v = *(const float4*)(nodes + ro + c);
      v.x *= fm; v.y *= fm; v.z *= fm; v.w *= fm;
      *(float4*)(x + ro + c) = v;
      float vv[4] = {v.x, v.y, v.z, v.w};
      bf16x4 hh, ll;
#pragma unroll
      for (int k = 0; k < 4; ++k) {
        bf16_t hi = f2b(vv[k]);
        hh[k] = hi;
        ll[k] = f2b(vv[k] - b2f(hi));
      }
      *(bf16x4*)(xhi + ro + c) = hh;
      *(bf16x4*)(xlo + ro + c) = ll;
      s += v.x * v.x + v.y * v.y + v.z * v.z + v.w * v.w;
    }
    sq[b * 512 + n] = s;
    flag[h] = (mk != 0);
    bal[h] = __ballot(flag[h]);
    if (lane == 0) cnts[h * 4 + w] = __popcll(bal[h]);
  }
  __syncthreads();
  if (t == 0) {
    int a = 0;
    for (int c = 0; c < 8; ++c) { basep[c] = a; a += cnts[c]; }
    vcnt[b] = a;
  }
  __syncthreads();
#pragma unroll
  for (int h = 0; h < 2; ++h) {
    if (flag[h]) {
      const unsigned long long lt = (lane == 0) ? 0ull : (~0ull >> (64 - lane));
      const int pos = basep[h * 4 + w] + __popcll(bal[h] & lt);
      vlist[b * 512 + pos] = h * 256 + t;
    }
  }
}

// ---------------- Kernel B: distances + top-16 (self excluded), row-parallel -------
// Lane = (row i = receiver, d = dim-group / candidate column). Per candidate: one
// broadcast ds_read_b128 + 4 fma + 4-DPP row-sum; lane d==c%16 keeps the dot.
// Selection: per-lane sorted 16-halves of (dist<<32|idx) u64 keys; 16 rounds of
// {head-min, 4-DPP row-min (uniform in-row), predicated pop}. All 4 receivers of a
// wave complete in the same 16 rounds. Equivalent to jax.lax.top_k(-dist,K+1)[1:]
// (ascending (dist,idx), drop rank0 = self).
__global__ void __launch_bounds__(256) kknn(const float* __restrict__ x,
    const float* __restrict__ sq, const int* __restrict__ vlist,
    const int* __restrict__ vcnt, int* __restrict__ idxg) {
  const int b = blockIdx.x & 63, tile = blockIdx.x >> 6;
  const int nv = vcnt[b];
  if (tile * 16 >= nv) return;  // block-uniform, before any barrier
  const int t = threadIdx.x, lane = t & 63, w = t >> 6;
  const int i = lane >> 4, d = lane & 15;
  __shared__ float sqs[512];
  __shared__ int vls[512];
  __shared__ __align__(16) float xr[16 * 64];   // 4 KB receiver rows
  __shared__ __align__(16) float xc[64 * 68];   // 17.4 KB candidate chunk
  for (int k = t; k < 512; k += 256) { sqs[k] = sq[b * 512 + k]; vls[k] = vlist[b * 512 + k]; }
  __syncthreads();
  const float* xb = x + (size_t)b * 512 * 64;
  {  // stage 16 receiver rows: 16 threads per row
    const int r = t >> 4, f4 = (t & 15) * 4;
    const int slot = tile * 16 + r;
    const int row = vls[slot < nv ? slot : 0];
    *(float4*)(xr + r * 64 + f4) = *(const float4*)(xb + (size_t)row * 64 + f4);
  }
  const int rslot = tile * 16 + w * 4 + i;
  const bool vrow = (rslot < nv);
  const int nrow = vls[rslot < nv ? rslot : 0];
  const float sqn = sqs[nrow];
  __syncthreads();
  const float4 xn = *(const float4*)(xr + (w * 4 + i) * 64 + d * 4);  // once, in regs

  float dotv[32];
#pragma unroll
  for (int j = 0; j < 32; ++j) dotv[j] = 0.f;

#pragma unroll
  for (int cb = 0; cb < 8; ++cb) {
    if (cb * 64 < nv) {  // uniform
      __syncthreads();
      {  // stage 64 candidate rows: 4 float4 per thread
        const int fo = (t & 15) * 4;
#pragma unroll
        for (int p = 0; p < 4; ++p) {
          const int cl = (t >> 4) + p * 16;
          const int c = cb * 64 + cl;
          if (c < nv)
            *(float4*)(xc + cl * 68 + fo) = *(const float4*)(xb + (size_t)vls[c] * 64 + fo);
        }
      }
      __syncthreads();
#pragma unroll
      for (int q = 0; q < 4; ++q) {
        float dq = 0.f;
#pragma unroll 4
        for (int cc = 0; cc < 16; ++cc) {
          const float4 xm = *(const float4*)(xc + (q * 16 + cc) * 68 + d * 4);
          float p = xn.x * xm.x;
          p = fmaf(xn.y, xm.y, p);
          p = fmaf(xn.z, xm.z, p);
          p = fmaf(xn.w, xm.w, p);
          p = rowsum_f32(p);          // full dot, uniform within row
          dq = (d == cc) ? p : dq;    // lane cc keeps candidate q*16+cc
        }
        dotv[cb * 4 + q] = dq;        // static index
      }
    }
  }

  const u64 INF64 = ~0ull;
  // keys: candidate c = j*16 + d belongs to this lane's slot j
  u64 s1[16], s2[16];
#pragma unroll
  for (int j = 0; j < 16; ++j) { s1[j] = INF64; s2[j] = INF64; }
#pragma unroll
  for (int j = 0; j < 32; ++j) {
    if (j * 16 < nv) {  // uniform
      const int c = j * 16 + d;
      const int m = vls[c < nv ? c : 0];
      const float dd = fabsf(sqn + sqs[m] - 2.f * dotv[j]);
      const u64 key = (((u64)__float_as_uint(dd)) << 32) | (unsigned)m;
      const bool ok = (c < nv) && (m != nrow);
      if (j < 16) s1[j] = ok ? key : INF64;
      else        s2[j - 16] = ok ? key : INF64;
    }
  }
  bitonic16(s1);
  const bool two = (nv > 256);  // uniform
  if (two) bitonic16(s2);

  int res = nrow;
#pragma unroll
  for (int ts = 0; ts < 16; ++ts) {
    const u64 head = two ? u64min(s1[0], s2[0]) : s1[0];
    const u64 wmin = rowmin_u64(head);
    if (d == ts) res = (wmin == INF64) ? nrow : (int)(unsigned)(wmin & 0xffffffffull);
    const bool w1 = (wmin != INF64) && (s1[0] == wmin);
#pragma unroll
    for (int k = 0; k < 15; ++k) s1[k] = w1 ? s1[k + 1] : s1[k];
    s1[15] = w1 ? INF64 : s1[15];
    if (two) {
      const bool w2 = (wmin != INF64) && (s2[0] == wmin);
#pragma unroll
      for (int k = 0; k < 15; ++k) s2[k] = w2 ? s2[k + 1] : s2[k];
      s2[15] = w2 ? INF64 : s2[15];
    }
  }
  // lane (i,d) holds round-d winner for receiver nrow: one parallel store
  if (vrow) idxg[((size_t)b * 512 + nrow) * 16 + d] = res;
}

// ---------------- Kernel C: edge MLP over COMPACTED valid receivers ----------------
// Weights staged in 16 KB phases (2 slabs per barrier-pair): 16 barriers total.
// L1: A' = [E_hi | E_lo] from xhi/xlo planes, B' = [W1_hi; W1_hi]
// L2: A' = [H_hi | H_hi] via per-wave hfrag,  B' = [W2_hi; W2_lo]
__global__ void __launch_bounds__(256) kedge(const bf16_t* __restrict__ xhi,
    const bf16_t* __restrict__ xlo, const int* __restrict__ idxg,
    const int* __restrict__ vlist, const int* __restrict__ vcnt,
    const bf16_t* __restrict__ W1p, const bf16_t* __restrict__ W2p,
    const float* __restrict__ be1, const float* __restrict__ be2,
    float* __restrict__ pooled) {
  const int bb = blockIdx.x >> 6, tile = blockIdx.x & 63;
  const int nv = vcnt[bb];
  if (tile * 8 >= nv) return;  // block-uniform, before any barrier
  __shared__ __align__(16) bf16_t wbuf[8192];          // 16 KB: 2 slabs per phase
  __shared__ __align__(16) bf16_t hfrag[4][2][2048];   // 32 KB
  const int t = threadIdx.x, lane = t & 63, w = t >> 6;
  const int q = lane >> 4, e = lane & 15;

  int gid[2]; bool act[2]; int sv[2];
#pragma unroll
  for (int u = 0; u < 2; ++u) {
    const int slot = tile * 8 + w * 2 + u;
    act[u] = (slot < nv);
    gid[u] = act[u] ? (bb * 512 + vlist[bb * 512 + slot]) : 0;
    sv[u] = act[u] ? idxg[(size_t)gid[u] * 16 + e] : 0;
  }

  f32x4 acc[2][8];
#pragma unroll
  for (int u = 0; u < 2; ++u)
#pragma unroll
    for (int nt = 0; nt < 8; ++nt) acc[u][nt] = zero4();

  // ---- Layer 1: 4 phases x 2 slabs ----
  for (int p = 0; p < 4; ++p) {
    __syncthreads();
    {
      const uint4* src = (const uint4*)(W1p + (size_t)p * 8192);
      uint4* dst = (uint4*)wbuf;
#pragma unroll
      for (int i = 0; i < 4; ++i) dst[t + 256 * i] = src[t + 256 * i];
    }
    __syncthreads();
#pragma unroll
    for (int sl = 0; sl < 2; ++sl) {
      const int s = p * 2 + sl;
      const bool wantlo = (s >= 4);
      const int sr = s & 3, half = sr >> 1, inner = sr & 1;
      const int col = inner * 32 + q * 8;
      const bf16_t* plane = wantlo ? xlo : xhi;
      bf16x8 af[2];
#pragma unroll
      for (int u = 0; u < 2; ++u) {
        if (act[u]) {
          const int row = half ? (bb * 512 + sv[u]) : gid[u];
          af[u] = *(const bf16x8*)(plane + (size_t)row * 64 + col);
        }
      }
#pragma unroll
      for (int nt = 0; nt < 8; ++nt) {
        const bf16x8 bfv = *(const bf16x8*)(wbuf + sl * 4096 + (nt * 64 + lane) * 8);
#pragma unroll
        for (int u = 0; u < 2; ++u)
          if (act[u]) acc[u][nt] = __builtin_amdgcn_mfma_f32_16x16x32_bf16(af[u], bfv, acc[u][nt], 0, 0, 0);
      }
    }
  }

  // ---- Epilogue 1: bias+relu -> bf16 hi -> per-wave lane-linear A-frag buffer ----
#pragma unroll
  for (int u = 0; u < 2; ++u) {
    if (act[u]) {
#pragma unroll
      for (int nt = 0; nt < 8; ++nt) {
        const int cc = nt * 16 + e;
        const float bv = be1[cc];
        const int base = ((cc >> 5) * 64 + (q * 4) + 16 * ((cc >> 3) & 3)) * 8 + (cc & 7);
#pragma unroll
        for (int r = 0; r < 4; ++r) {
          float h = fmaxf(acc[u][nt][r] + bv, 0.f);
          hfrag[w][u][base + r * 8] = f2b(h);
        }
      }
    }
  }

  // ---- Layer 2: 4 phases x 2 slabs ----
#pragma unroll
  for (int u = 0; u < 2; ++u)
#pragma unroll
    for (int nt = 0; nt < 8; ++nt) acc[u][nt] = zero4();

  for (int p = 0; p < 4; ++p) {
    __syncthreads();
    {
      const uint4* src = (const uint4*)(W2p + (size_t)p * 8192);
      uint4* dst = (uint4*)wbuf;
#pragma unroll
      for (int i = 0; i < 4; ++i) dst[t + 256 * i] = src[t + 256 * i];
    }
    __syncthreads();
#pragma unroll
    for (int sl = 0; sl < 2; ++sl) {
      const int s = p * 2 + sl;
      const int f = s & 3;
      bf16x8 af[2];
#pragma unroll
      for (int u = 0; u < 2; ++u)
        if (act[u]) af[u] = *(const bf16x8*)(&hfrag[w][u][(f * 64 + lane) * 8]);
#pragma unroll
      for (int nt = 0; nt < 8; ++nt) {
        const bf16x8 bfv = *(const bf16x8*)(wbuf + sl * 4096 + (nt * 64 + lane) * 8);
#pragma unroll
        for (int u = 0; u < 2; ++u)
          if (act[u]) acc[u][nt] = __builtin_amdgcn_mfma_f32_16x16x32_bf16(af[u], bfv, acc[u][nt], 0, 0, 0);
      }
    }
  }

  // ---- Epilogue 2: bias+relu, mean over 16 edges (cnt==16 exactly) ----
#pragma unroll
  for (int u = 0; u < 2; ++u) {
    if (act[u]) {
#pragma unroll
      for (int nt = 0; nt < 8; ++nt) {
        const float bv = be2[nt * 16 + e];
        float part = 0.f;
#pragma unroll
        for (int r = 0; r < 4; ++r) part += fmaxf(acc[u][nt][r] + bv, 0.f);
        part += __shfl_xor(part, 16, 64);
        part += __shfl_xor(part, 32, 64);
        if (lane < 16) pooled[(size_t)gid[u] * 128 + nt * 16 + lane] = part * 0.0625f;
      }
    }
  }
}

// ---------------- Kernel D: node MLP (wave = 2 tiles of 16 nodes) ------------------
__global__ void __launch_bounds__(256) knode(const float* __restrict__ x,
    const float* __restrict__ pooled, const int* __restrict__ mask,
    const bf16_t* __restrict__ Wn1p, const bf16_t* __restrict__ Wn2p,
    const float* __restrict__ bn1, const float* __restrict__ bn2,
    float* __restrict__ out) {
  __shared__ __align__(16) bf16_t slab[4096];          // 8 KB
  __shared__ __align__(16) bf16_t hfrag[4][2][2048];   // 32 KB
  const int t = threadIdx.x, lane = t & 63, w = t >> 6;
  const int q = lane >> 4, e = lane & 15;
  int nodebase[2];
#pragma unroll
  for (int u = 0; u < 2; ++u) nodebase[u] = (blockIdx.x * 8 + w * 2 + u) * 16;

  f32x4 acc[2][8];
#pragma unroll
  for (int u = 0; u < 2; ++u)
#pragma unroll
    for (int nt = 0; nt < 8; ++nt) acc[u][nt] = zero4();

  // ---- Layer 1 (12 slabs) ----
  for (int s = 0; s < 12; ++s) {
    __syncthreads();
    {
      const uint4* src = (const uint4*)(Wn1p + (size_t)s * 4096);
      uint4* dst = (uint4*)slab;
      for (int i = t; i < 512; i += 256) dst[i] = src[i];
    }
    __syncthreads();
    const bool wantlo = (s >= 6);
    const int sr = wantlo ? (s - 6) : s;
    const int col = sr * 32 + q * 8;  // [0,192); region uniform per s
    bf16x8 af[2];
#pragma unroll
    for (int u = 0; u < 2; ++u) {
      const int node = nodebase[u] + e;
      const float* p = (col < 64) ? (x + (size_t)node * 64 + col)
                                  : (pooled + (size_t)node * 128 + (col - 64));
      af[u] = make_frag(p, wantlo);
    }
#pragma unroll
    for (int nt = 0; nt < 8; ++nt) {
      const bf16x8 bfv = *(const bf16x8*)(slab + (nt * 64 + lane) * 8);
#pragma unroll
      for (int u = 0; u < 2; ++u)
        acc[u][nt] = __builtin_amdgcn_mfma_f32_16x16x32_bf16(af[u], bfv, acc[u][nt], 0, 0, 0);
    }
  }

  // ---- Epilogue 1 ----
#pragma unroll
  for (int u = 0; u < 2; ++u) {
#pragma unroll
    for (int nt = 0; nt < 8; ++nt) {
      const int cc = nt * 16 + e;
      const float bv = bn1[cc];
      const int base = ((cc >> 5) * 64 + (q * 4) + 16 * ((cc >> 3) & 3)) * 8 + (cc & 7);
#pragma unroll
      for (int r = 0; r < 4; ++r) {
        float h = fmaxf(acc[u][nt][r] + bv, 0.f);
        hfrag[w][u][base + r * 8] = f2b(h);
      }
    }
  }

  // ---- Layer 2 (8 slabs of 4 KB, N=64 -> 4 ntiles) ----
  f32x4 acc2[2][4];
#pragma unroll
  for (int u = 0; u < 2; ++u)
#pragma unroll
    for (int nt = 0; nt < 4; ++nt) acc2[u][nt] = zero4();

  for (int s = 0; s < 8; ++s) {
    __syncthreads();
    {
      const uint4* src = (const uint4*)(Wn2p + (size_t)s * 2048);
      uint4* dst = (uint4*)slab;
      for (int i = t; i < 256; i += 256) dst[i] = src[i];
    }
    __syncthreads();
    const int f = s & 3;
    bf16x8 af[2];
#pragma unroll
    for (int u = 0; u < 2; ++u)
      af[u] = *(const bf16x8*)(&hfrag[w][u][(f * 64 + lane) * 8]);
#pragma unroll
    for (int nt = 0; nt < 4; ++nt) {
      const bf16x8 bfv = *(const bf16x8*)(slab + (nt * 64 + lane) * 8);
#pragma unroll
      for (int u = 0; u < 2; ++u)
        acc2[u][nt] = __builtin_amdgcn_mfma_f32_16x16x32_bf16(af[u], bfv, acc2[u][nt], 0, 0, 0);
    }
  }

  // ---- Final: + bn2, * mask, store ----
#pragma unroll
  for (int u = 0; u < 2; ++u) {
    int mm[4];
#pragma unroll
    for (int r = 0; r < 4; ++r) mm[r] = mask[nodebase[u] + q * 4 + r];
#pragma unroll
    for (int nt = 0; nt < 4; ++nt) {
      const float bv = bn2[nt * 16 + e];
#pragma unroll
      for (int r = 0; r < 4; ++r) {
        const int node = nodebase[u] + q * 4 + r;
        out[(size_t)node * 64 + nt * 16 + e] = (acc2[u][nt][r] + bv) * (float)mm[r];
      }
    }
  }
}

// ---------------- Launch ----------------
extern "C" void kernel_launch(void* const* d_in, const int* in_sizes, int n_in,
                              void* d_out, int out_size, void* d_ws, size_t ws_size,
                              hipStream_t stream) {
  const float* nodes = (const float*)d_in[0];
  const int*   mask  = (const int*)d_in[1];
  const float* We1   = (const float*)d_in[2];
  const float* be1   = (const float*)d_in[3];
  const float* We2   = (const float*)d_in[4];
  const float* be2   = (const float*)d_in[5];
  const float* Wn1   = (const float*)d_in[6];
  const float* bn1   = (const float*)d_in[7];
  const float* Wn2   = (const float*)d_in[8];
  const float* bn2   = (const float*)d_in[9];
  float* out = (float*)d_out;

  char* p = (char*)d_ws;
  auto alloc = [&](size_t bytes) -> char* {
    char* r = p;
    p += (bytes + 255) & ~(size_t)255;
    return r;
  };
  float*  x      = (float*)alloc((size_t)32768 * 64 * 4);
  bf16_t* xhi    = (bf16_t*)alloc((size_t)32768 * 64 * 2);
  bf16_t* xlo    = (bf16_t*)alloc((size_t)32768 * 64 * 2);
  float*  sq     = (float*)alloc((size_t)32768 * 4);
  int*    vlist  = (int*)alloc((size_t)32768 * 4);
  int*    vcnt   = (int*)alloc((size_t)64 * 4);
  int*    idxg   = (int*)alloc((size_t)32768 * 16 * 4);
  float*  pooled = (float*)alloc((size_t)32768 * 128 * 4);
  bf16_t* W1p    = (bf16_t*)alloc((size_t)8 * 8 * 64 * 8 * 2);
  bf16_t* W2p    = (bf16_t*)alloc((size_t)8 * 8 * 64 * 8 * 2);
  bf16_t* Wn1p   = (bf16_t*)alloc((size_t)12 * 8 * 64 * 8 * 2);
  bf16_t* Wn2p   = (bf16_t*)alloc((size_t)8 * 4 * 64 * 8 * 2);
  if ((size_t)(p - (char*)d_ws) > ws_size) return;  // workspace too small -> loud failure

  kpack<<<64, 256, 0, stream>>>(We1, We2, Wn1, Wn2, W1p, W2p, Wn1p, Wn2p);
  kprep<<<64, 256, 0, stream>>>(nodes, mask, x, xhi, xlo, sq, vlist, vcnt);
  kknn<<<2048, 256, 0, stream>>>(x, sq, vlist, vcnt, idxg);
  kedge<<<4096, 256, 0, stream>>>(xhi, xlo, idxg, vlist, vcnt, W1p, W2p, be1, be2, pooled);
  knode<<<256, 256, 0, stream>>>(x, pooled, mask, Wn1p, Wn2p, bn1, bn2, out);
}